// Round 11
// baseline (97.431 us; speedup 1.0000x reference)
//
#include <hip/hip_runtime.h>

// ParallelLinear: out[b,t,o] = sum_i x[b,t,i] * W[t,o,i] + bias[t,o]
// B=512, T=1024, ISIZE=OSIZE=64, fp32 in/out.
//
// v11 = v10 (1KB-granule experiment with pre-converted W in d_ws) + the
// ws_size guard that v10 lacked. v10's container death is consistent with
// an OOB write to an undersized workspace; if ws_size < 16.8MB we now fall
// back to the verified R6 kernel (72.4us, absmax 0.0156) instead of
// corrupting memory.
//
// Primary path (needs 16.8MB workspace):
//  - w_conv pre-kernel: W fp32 -> bf16 hi/lo planes in d_ws (~6us).
//  - pl_kernel: block = 4 consecutive t's x 32 rows -> x reads and out
//    writes are 1KB contiguous per b-row (tests the DRAM-activate granule
//    theory for the 3.1 TB/s = half-of-streaming cap seen in R0/R2/R6).
//  - W-frags are direct 16B loads of ready fragments: compiler demotion to
//    reloads (R4/R8/R9 failure mode) becomes harmless L2 hits.
//  - X planes 32KB LDS -> 4 blocks/CU; XCD-bijective remap keeps each
//    quad's 16 chunk-blocks on one XCD (W L2-hot).
// Numerics (both paths): verified 3-term bf16 hi/lo split.

#define T_DIM 1024
#define B_DIM 512
#define KSZ 64
#define OSZ 64
#define WELEMS (T_DIM * OSZ * KSZ)     // 4194304

typedef __attribute__((ext_vector_type(8))) short short8;   // 8 bf16
typedef __attribute__((ext_vector_type(4))) short short4v;
typedef __attribute__((ext_vector_type(4))) float f32x4;

static __device__ __forceinline__ unsigned short f2bf(float f) {
    unsigned u = __float_as_uint(f);
    u += 0x7FFFu + ((u >> 16) & 1u);          // RNE
    return (unsigned short)(u >> 16);
}
static __device__ __forceinline__ float bf2f(unsigned short h) {
    return __uint_as_float((unsigned)h << 16);
}

// ======================= primary path (workspace) ==========================

#define ROWS 32
#define NT 4
#define NCHUNK (B_DIM / ROWS)          // 16

__global__ __launch_bounds__(256) void w_conv(
    const float* __restrict__ W, short* __restrict__ ws)
{
    const size_t i = ((size_t)blockIdx.x * 256 + threadIdx.x) * 4;
    float4 w = *(const float4*)(W + i);
    float a[4] = {w.x, w.y, w.z, w.w};
    short4v h, lo;
    #pragma unroll
    for (int j = 0; j < 4; ++j) {
        unsigned short hh = f2bf(a[j]);
        h[j]  = (short)hh;
        lo[j] = (short)f2bf(a[j] - bf2f(hh));
    }
    *(short4v*)(ws + i)          = h;
    *(short4v*)(ws + WELEMS + i) = lo;
}

__global__ __launch_bounds__(256, 4) void pl_kernel(
    const float* __restrict__ x,
    const short* __restrict__ Wb,     // [hi plane][lo plane], layout [t][o][k]
    const float* __restrict__ bias,
    float* __restrict__ out)
{
    __shared__ short Xh[NT * ROWS * KSZ];   // 16 KB
    __shared__ short Xl[NT * ROWS * KSZ];   // 16 KB

    // XCD-bijective remap: xcd = orig&7 owns quads [32*xcd, 32*xcd+32)
    const int orig  = blockIdx.x;
    const int quad  = (orig & 7) * 32 + (orig >> 7);   // 0..255
    const int chunk = (orig >> 3) & 15;                // 0..15
    const int T0    = quad * NT;
    const int row0  = chunk * ROWS;
    const int tid   = threadIdx.x;
    const int ws    = tid >> 6;            // wave id = t-slot 0..3
    const int l     = tid & 63;
    const int n     = l & 15;
    const int kq    = l >> 4;              // 0..3

    // ===== X staging: 1KB-contiguous reads -> swizzled bf16 hi/lo planes =====
    {
        const int sr   = tid >> 3;
        const int sq   = (tid >> 1) & 3;
        const int half = tid & 1;
        const float* xp = x + ((size_t)(row0 + sr) * T_DIM + (T0 + sq)) * KSZ + 32 * half;
        short* xh = Xh + sq * (ROWS * KSZ) + sr * KSZ;
        short* xl = Xl + sq * (ROWS * KSZ) + sr * KSZ;
        const int swz = (sr & 7) ^ sq;
        #pragma unroll
        for (int bb = 0; bb < 4; ++bb) {
            float4 f0 = *(const float4*)(xp + bb * 8);
            float4 f1 = *(const float4*)(xp + bb * 8 + 4);
            float a[8] = {f0.x, f0.y, f0.z, f0.w, f1.x, f1.y, f1.z, f1.w};
            short8 h, lo;
            #pragma unroll
            for (int j = 0; j < 8; ++j) {
                unsigned short hh = f2bf(a[j]);
                h[j]  = (short)hh;
                lo[j] = (short)f2bf(a[j] - bf2f(hh));
            }
            const int g = (half * 4 + bb) ^ swz;   // granule position
            *(short8*)(xh + g * 8) = h;
            *(short8*)(xl + g * 8) = lo;
        }
    }

    __syncthreads();

    // ===== A-frags from plane ws: lane holds A[row=16m+n][k=(ks*4+kq)*8+j] =====
    short8 ah[2][2], al[2][2];
    #pragma unroll
    for (int m = 0; m < 2; ++m) {
        const int arow = 16 * m + n;
        const short* ph = Xh + ws * (ROWS * KSZ) + arow * KSZ;
        const short* pl = Xl + ws * (ROWS * KSZ) + arow * KSZ;
        const int s2 = (arow & 7) ^ ws;
        #pragma unroll
        for (int ks = 0; ks < 2; ++ks) {
            const int g = (ks * 4 + kq) ^ s2;
            ah[m][ks] = *(const short8*)(ph + g * 8);
            al[m][ks] = *(const short8*)(pl + g * 8);
        }
    }

    // ===== MFMA: W-frags are direct 16B loads of preconverted bf16 =====
    // B-frag layout (R6-verified): lane holds W[o=16ct+n][k=(ks*4+kq)*8+j]
    const int t = T0 + ws;
    f32x4 acc[2][4] = {};
    #pragma unroll
    for (int ct = 0; ct < 4; ++ct) {
        const size_t wbase = ((size_t)t * OSZ + 16 * ct + n) * KSZ + kq * 8;
        #pragma unroll
        for (int ks = 0; ks < 2; ++ks) {
            short8 wh = *(const short8*)(Wb + wbase + ks * 32);
            short8 wl = *(const short8*)(Wb + WELEMS + wbase + ks * 32);
            #pragma unroll
            for (int m = 0; m < 2; ++m) {
                acc[m][ct] = __builtin_amdgcn_mfma_f32_16x16x32_bf16(ah[m][ks], wh, acc[m][ct], 0, 0, 0);
                acc[m][ct] = __builtin_amdgcn_mfma_f32_16x16x32_bf16(al[m][ks], wh, acc[m][ct], 0, 0, 0);
                acc[m][ct] = __builtin_amdgcn_mfma_f32_16x16x32_bf16(ah[m][ks], wl, acc[m][ct], 0, 0, 0);
            }
        }
    }

    // ===== epilogue: direct stores (C/D map: col = n, row = 4*kq + j) =====
    #pragma unroll
    for (int ct = 0; ct < 4; ++ct) {
        const float bv = bias[(size_t)t * OSZ + 16 * ct + n];
        #pragma unroll
        for (int m = 0; m < 2; ++m) {
            #pragma unroll
            for (int j = 0; j < 4; ++j) {
                const size_t b = (size_t)row0 + 16 * m + 4 * kq + j;
                out[(b * T_DIM + t) * OSZ + 16 * ct + n] = acc[m][ct][j] + bv;
            }
        }
    }
}

// ======================= fallback path (R6 verbatim) =======================

#define FROWS 64

__global__ __launch_bounds__(256, 4) void pl_fallback(
    const float* __restrict__ x,
    const float* __restrict__ W,
    const float* __restrict__ bias,
    float* __restrict__ out)
{
    __shared__ unsigned short Xh[FROWS * KSZ];
    __shared__ unsigned short Xl[FROWS * KSZ];
    __shared__ unsigned short Wh[OSZ * KSZ];
    __shared__ unsigned short Wl[OSZ * KSZ];

    const int t     = blockIdx.x >> 3;
    const int chunk = blockIdx.x & 7;
    const int row0  = chunk * FROWS;
    const int tid   = threadIdx.x;

    const int sr = tid >> 2;
    const int kc = tid & 3;

    {
        const float* xp = x + ((size_t)(row0 + sr) * T_DIM + t) * KSZ + 16 * kc;
        float4 f0 = *(const float4*)(xp);
        float4 f1 = *(const float4*)(xp + 4);
        float4 f2 = *(const float4*)(xp + 8);
        float4 f3 = *(const float4*)(xp + 12);
        float a[8]  = {f0.x, f0.y, f0.z, f0.w, f1.x, f1.y, f1.z, f1.w};
        float b2[8] = {f2.x, f2.y, f2.z, f2.w, f3.x, f3.y, f3.z, f3.w};
        unsigned short h0[8], l0[8], h1[8], l1[8];
        #pragma unroll
        for (int j = 0; j < 8; ++j) {
            unsigned short hh = f2bf(a[j]);
            h0[j] = hh; l0[j] = f2bf(a[j] - bf2f(hh));
            unsigned short h2 = f2bf(b2[j]);
            h1[j] = h2; l1[j] = f2bf(b2[j] - bf2f(h2));
        }
        const int p0 = (((2 * kc)     ^ (sr & 7)) << 3);
        const int p1 = (((2 * kc + 1) ^ (sr & 7)) << 3);
        #pragma unroll
        for (int j = 0; j < 8; ++j) {
            Xh[sr * KSZ + p0 + j] = h0[j];
            Xl[sr * KSZ + p0 + j] = l0[j];
            Xh[sr * KSZ + p1 + j] = h1[j];
            Xl[sr * KSZ + p1 + j] = l1[j];
        }
    }
    {
        const float* wp = W + (size_t)t * (OSZ * KSZ) + (size_t)sr * KSZ + 16 * kc;
        float4 f0 = *(const float4*)(wp);
        float4 f1 = *(const float4*)(wp + 4);
        float4 f2 = *(const float4*)(wp + 8);
        float4 f3 = *(const float4*)(wp + 12);
        float a[8]  = {f0.x, f0.y, f0.z, f0.w, f1.x, f1.y, f1.z, f1.w};
        float b2[8] = {f2.x, f2.y, f2.z, f2.w, f3.x, f3.y, f3.z, f3.w};
        unsigned short h0[8], l0[8], h1[8], l1[8];
        #pragma unroll
        for (int j = 0; j < 8; ++j) {
            unsigned short hh = f2bf(a[j]);
            h0[j] = hh; l0[j] = f2bf(a[j] - bf2f(hh));
            unsigned short h2 = f2bf(b2[j]);
            h1[j] = h2; l1[j] = f2bf(b2[j] - bf2f(h2));
        }
        const int p0 = (((2 * kc)     ^ (sr & 7)) << 3);
        const int p1 = (((2 * kc + 1) ^ (sr & 7)) << 3);
        #pragma unroll
        for (int j = 0; j < 8; ++j) {
            Wh[sr * KSZ + p0 + j] = h0[j];
            Wl[sr * KSZ + p0 + j] = l0[j];
            Wh[sr * KSZ + p1 + j] = h1[j];
            Wl[sr * KSZ + p1 + j] = l1[j];
        }
    }

    __syncthreads();

    const int w  = tid >> 6;
    const int l  = tid & 63;
    const int kq = l >> 4;

    const int arow = 16 * w + (l & 15);
    short8 ah[2], al[2];
    #pragma unroll
    for (int ks = 0; ks < 2; ++ks) {
        const int kb  = ks * 4 + kq;
        const int pos = (kb ^ (arow & 7)) << 3;
        ah[ks] = *(const short8*)&Xh[arow * KSZ + pos];
        al[ks] = *(const short8*)&Xl[arow * KSZ + pos];
    }

    f32x4 acc[4] = {};
    #pragma unroll
    for (int ct = 0; ct < 4; ++ct) {
        const int brow = 16 * ct + (l & 15);
        #pragma unroll
        for (int ks = 0; ks < 2; ++ks) {
            const int kb  = ks * 4 + kq;
            const int pos = (kb ^ (brow & 7)) << 3;
            short8 bh = *(const short8*)&Wh[brow * KSZ + pos];
            short8 bl = *(const short8*)&Wl[brow * KSZ + pos];
            acc[ct] = __builtin_amdgcn_mfma_f32_16x16x32_bf16(ah[ks], bh, acc[ct], 0, 0, 0);
            acc[ct] = __builtin_amdgcn_mfma_f32_16x16x32_bf16(al[ks], bh, acc[ct], 0, 0, 0);
            acc[ct] = __builtin_amdgcn_mfma_f32_16x16x32_bf16(ah[ks], bl, acc[ct], 0, 0, 0);
        }
    }

    #pragma unroll
    for (int ct = 0; ct < 4; ++ct) {
        const float bv = bias[(size_t)t * OSZ + 16 * ct + (l & 15)];
        #pragma unroll
        for (int j = 0; j < 4; ++j) {
            const size_t b = (size_t)row0 + 16 * w + 4 * kq + j;
            out[(b * T_DIM + t) * OSZ + 16 * ct + (l & 15)] = acc[ct][j] + bv;
        }
    }
}

extern "C" void kernel_launch(void* const* d_in, const int* in_sizes, int n_in,
                              void* d_out, int out_size, void* d_ws, size_t ws_size,
                              hipStream_t stream) {
    const float* x    = (const float*)d_in[0];
    const float* W    = (const float*)d_in[1];
    const float* bias = (const float*)d_in[2];
    float* out        = (float*)d_out;

    const size_t need = (size_t)2 * WELEMS * sizeof(short);   // 16.8 MB
    if (d_ws != nullptr && ws_size >= need) {
        short* wb = (short*)d_ws;
        dim3 blk(256);
        w_conv<<<dim3(WELEMS / (256 * 4)), blk, 0, stream>>>(W, wb);
        pl_kernel<<<dim3((T_DIM / NT) * NCHUNK), blk, 0, stream>>>(x, wb, bias, out);
    } else {
        dim3 blk(256);
        pl_fallback<<<dim3(T_DIM * (B_DIM / FROWS)), blk, 0, stream>>>(x, W, bias, out);
    }
}

// Round 12
// 64.418 us; speedup vs baseline: 1.5125x; 1.5125x over previous
//
#include <hip/hip_runtime.h>

// ParallelLinear: out[b,t,o] = sum_i x[b,t,i] * W[t,o,i] + bias[t,o]
// B=512, T=1024, ISIZE=OSIZE=64, fp32 in/out.
//
// v12 = R6's verified MFMA engine (72.4us best) + persistent per-t blocks +
// NON-DRAINING barriers. Diagnosis across R0-R11: time never tracked HBM
// traffic (R6 263MB/86us vs R11 205MB/96us) -> latency-exposure-bound, not
// BW-bound. Root cause of every failed pipeline: __syncthreads() emits
// s_waitcnt vmcnt(0) (compiler semantics), draining register prefetches at
// the barrier. Fix: lgkmcnt(0)-only asm + raw s_barrier -> next chunk's
// global loads stay in flight under the whole compute phase (T4/m218).
// 1024 persistent blocks (one per t), 32KB LDS -> 4 blocks/CU, all
// co-resident; ~16KB/block continuously outstanding >> Little's-law need.
// Numerics: the 6x-verified 3-term bf16 hi/lo split (absmax 0.0156).

#define T_DIM 1024
#define B_DIM 512
#define KSZ 64
#define OSZ 64
#define ROWS 64
#define NCH (B_DIM / ROWS)   // 8

typedef __attribute__((ext_vector_type(8))) short short8;   // 8 bf16
typedef __attribute__((ext_vector_type(4))) float f32x4;

static __device__ __forceinline__ unsigned short f2bf(float f) {
    unsigned u = __float_as_uint(f);
    u += 0x7FFFu + ((u >> 16) & 1u);          // RNE
    return (unsigned short)(u >> 16);
}
static __device__ __forceinline__ float bf2f(unsigned short h) {
    return __uint_as_float((unsigned)h << 16);
}

// lgkm-only barrier: LDS ordering preserved, global loads stay in flight.
#define LGKM_BARRIER() do {                                   \
    asm volatile("s_waitcnt lgkmcnt(0)" ::: "memory");        \
    __builtin_amdgcn_s_barrier();                             \
} while (0)

__global__ __launch_bounds__(256, 4) void pl_kernel(
    const float* __restrict__ x,
    const float* __restrict__ W,
    const float* __restrict__ bias,
    float* __restrict__ out)
{
    __shared__ short Xh[ROWS * KSZ];   // 8 KB  (swizzled bf16 hi plane)
    __shared__ short Xl[ROWS * KSZ];   // 8 KB
    __shared__ short Wh[OSZ * KSZ];    // 8 KB
    __shared__ short Wl[OSZ * KSZ];    // 8 KB   -> 32 KB total, 4 blocks/CU

    const int t   = blockIdx.x;        // 0..1023, persistent per t
    const int tid = threadIdx.x;

    // staging coords (R6-verified): thread = (row sr, 16-float chunk kc)
    const int sr = tid >> 2;           // 0..63
    const int kc = tid & 3;            // 0..3
    // compute coords (R6-verified)
    const int w  = tid >> 6;           // wave 0..3
    const int l  = tid & 63;
    const int n  = l & 15;
    const int kq = l >> 4;             // 0..3

    const size_t cstep = (size_t)ROWS * T_DIM * KSZ;   // floats per 64-row chunk
    const float* xp0 = x + ((size_t)sr * T_DIM + t) * KSZ + 16 * kc;

    // ---- prefetch chunk 0 (4 x b128, stay in flight under W staging) ----
    float4 pf0 = *(const float4*)(xp0);
    float4 pf1 = *(const float4*)(xp0 + 4);
    float4 pf2 = *(const float4*)(xp0 + 8);
    float4 pf3 = *(const float4*)(xp0 + 12);

    // ---- stage W[t] once (R6-verified swizzle, conflict-free) ----
    {
        const float* wp = W + (size_t)t * (OSZ * KSZ) + (size_t)sr * KSZ + 16 * kc;
        float4 g0 = *(const float4*)(wp);
        float4 g1 = *(const float4*)(wp + 4);
        float4 g2 = *(const float4*)(wp + 8);
        float4 g3 = *(const float4*)(wp + 12);
        float a[8]  = {g0.x, g0.y, g0.z, g0.w, g1.x, g1.y, g1.z, g1.w};
        float b2[8] = {g2.x, g2.y, g2.z, g2.w, g3.x, g3.y, g3.z, g3.w};
        short8 h0, l0, h1, l1;
        #pragma unroll
        for (int j = 0; j < 8; ++j) {
            unsigned short hh = f2bf(a[j]);
            h0[j] = (short)hh; l0[j] = (short)f2bf(a[j] - bf2f(hh));
            unsigned short h2 = f2bf(b2[j]);
            h1[j] = (short)h2; l1[j] = (short)f2bf(b2[j] - bf2f(h2));
        }
        const int p0 = (((2 * kc)     ^ (sr & 7)) << 3);
        const int p1 = (((2 * kc + 1) ^ (sr & 7)) << 3);
        *(short8*)&Wh[sr * KSZ + p0] = h0;
        *(short8*)&Wl[sr * KSZ + p0] = l0;
        *(short8*)&Wh[sr * KSZ + p1] = h1;
        *(short8*)&Wl[sr * KSZ + p1] = l1;
    }

    // hoist bias (per-thread, 4 scalars)
    float bv[4];
    #pragma unroll
    for (int ct = 0; ct < 4; ++ct)
        bv[ct] = bias[(size_t)t * OSZ + 16 * ct + n];

    const int p0 = (((2 * kc)     ^ (sr & 7)) << 3);
    const int p1 = (((2 * kc + 1) ^ (sr & 7)) << 3);

    for (int c = 0; c < NCH; ++c) {
        // ---- convert chunk c (compiler auto-waits vmcnt for pf regs here) ----
        float a[8]  = {pf0.x, pf0.y, pf0.z, pf0.w, pf1.x, pf1.y, pf1.z, pf1.w};
        float b2[8] = {pf2.x, pf2.y, pf2.z, pf2.w, pf3.x, pf3.y, pf3.z, pf3.w};
        short8 h0, l0, h1, l1;
        #pragma unroll
        for (int j = 0; j < 8; ++j) {
            unsigned short hh = f2bf(a[j]);
            h0[j] = (short)hh; l0[j] = (short)f2bf(a[j] - bf2f(hh));
            unsigned short h2 = f2bf(b2[j]);
            h1[j] = (short)h2; l1[j] = (short)f2bf(b2[j] - bf2f(h2));
        }

        if (c > 0) LGKM_BARRIER();       // all waves done reading Xs(c-1); vmcnt untouched

        *(short8*)&Xh[sr * KSZ + p0] = h0;
        *(short8*)&Xl[sr * KSZ + p0] = l0;
        *(short8*)&Xh[sr * KSZ + p1] = h1;
        *(short8*)&Xl[sr * KSZ + p1] = l1;

        // ---- issue prefetch for chunk c+1: in flight across the barrier ----
        if (c + 1 < NCH) {
            const float* xp = xp0 + (size_t)(c + 1) * cstep;
            pf0 = *(const float4*)(xp);
            pf1 = *(const float4*)(xp + 4);
            pf2 = *(const float4*)(xp + 8);
            pf3 = *(const float4*)(xp + 12);
        }

        LGKM_BARRIER();                  // Xs(c) visible; prefetch NOT drained

        // ---- compute (R6-verified): A-frags + 24 MFMA ----
        const int arow = 16 * w + n;
        short8 ah[2], al[2];
        #pragma unroll
        for (int ks = 0; ks < 2; ++ks) {
            const int pos = ((ks * 4 + kq) ^ (arow & 7)) << 3;
            ah[ks] = *(const short8*)&Xh[arow * KSZ + pos];
            al[ks] = *(const short8*)&Xl[arow * KSZ + pos];
        }

        f32x4 acc[4] = {};
        #pragma unroll
        for (int ct = 0; ct < 4; ++ct) {
            const int brow = 16 * ct + n;
            #pragma unroll
            for (int ks = 0; ks < 2; ++ks) {
                const int pos = ((ks * 4 + kq) ^ (brow & 7)) << 3;
                short8 bh = *(const short8*)&Wh[brow * KSZ + pos];
                short8 bl = *(const short8*)&Wl[brow * KSZ + pos];
                acc[ct] = __builtin_amdgcn_mfma_f32_16x16x32_bf16(ah[ks], bh, acc[ct], 0, 0, 0);
                acc[ct] = __builtin_amdgcn_mfma_f32_16x16x32_bf16(al[ks], bh, acc[ct], 0, 0, 0);
                acc[ct] = __builtin_amdgcn_mfma_f32_16x16x32_bf16(ah[ks], bl, acc[ct], 0, 0, 0);
            }
        }

        // ---- epilogue (R6-verified C/D map: col = n, row = 4*kq + j) ----
        const int row0 = c * ROWS;
        #pragma unroll
        for (int ct = 0; ct < 4; ++ct) {
            #pragma unroll
            for (int j = 0; j < 4; ++j) {
                const size_t b = (size_t)row0 + 16 * w + 4 * kq + j;
                out[(b * T_DIM + t) * OSZ + 16 * ct + n] = acc[ct][j] + bv[ct];
            }
        }
    }
}

extern "C" void kernel_launch(void* const* d_in, const int* in_sizes, int n_in,
                              void* d_out, int out_size, void* d_ws, size_t ws_size,
                              hipStream_t stream) {
    const float* x    = (const float*)d_in[0];
    const float* W    = (const float*)d_in[1];
    const float* bias = (const float*)d_in[2];
    float* out        = (float*)d_out;

    dim3 grid(T_DIM);                    // 1024 persistent blocks, 4/CU
    dim3 block(256);
    pl_kernel<<<grid, block, 0, stream>>>(x, W, bias, out);
}